// Round 10
// baseline (656.458 us; speedup 1.0000x reference)
//
#include <hip/hip_runtime.h>
#include <math.h>
#include <stdint.h>

#define BB 256
#define C_IN 7
#define TT 160
#define PATCH 10
#define D_MODEL 512
#define L_TOK 16
#define D_INNER 1024
#define D_STATE 16
#define DT_RANK 32
#define EPS 1e-5f
#define NROWS (BB*L_TOK)   // 4096
#define KPAD 96            // 70 padded to 3*32

typedef __bf16 bf16x8 __attribute__((ext_vector_type(8)));
typedef __bf16 bf16x4 __attribute__((ext_vector_type(4)));
typedef float  f32x4  __attribute__((ext_vector_type(4)));

__device__ __forceinline__ float siluf(float x){ return x / (1.f + __expf(-x)); }
__device__ __forceinline__ float softplusf(float x){ return (x > 20.f) ? x : log1pf(__expf(x)); }

__device__ __forceinline__ void gload_lds16(const void* gp, void* lp){
  __builtin_amdgcn_global_load_lds(
      (const __attribute__((address_space(1))) unsigned int*)(uintptr_t)gp,
      (__attribute__((address_space(3))) unsigned int*)(uintptr_t)lp, 16, 0, 0);
}

__device__ __forceinline__ float block_reduce_sum(float v, float* sred4){
  for(int off=32; off>0; off>>=1) v += __shfl_down(v, off, 64);
  int lane = threadIdx.x & 63, wid = threadIdx.x >> 6;
  if(lane==0) sred4[wid] = v;
  __syncthreads();
  if(threadIdx.x==0) sred4[0] = sred4[0]+sred4[1]+sred4[2]+sred4[3];
  __syncthreads();
  float r = sred4[0];
  __syncthreads();
  return r;
}

// ---------------------------------------------------------------------------
// transpose + fp32->bf16: in [z][K][N] f32 -> out [z][N][K] bf16
// ---------------------------------------------------------------------------
__global__ __launch_bounds__(256) void transpose_bf16_kernel(
    const float* __restrict__ in, __bf16* __restrict__ out, int K, int N)
{
  __shared__ float tile[32][33];
  size_t moff = (size_t)blockIdx.z * K * N;
  int n0 = blockIdx.x*32, k0 = blockIdx.y*32;
  int tx = threadIdx.x, ty = threadIdx.y;
  #pragma unroll
  for(int rr=0;rr<4;rr++)
    tile[ty+rr*8][tx] = in[moff + (size_t)(k0+ty+rr*8)*N + n0+tx];
  __syncthreads();
  #pragma unroll
  for(int rr=0;rr<4;rr++)
    out[moff + (size_t)(n0+ty+rr*8)*K + k0+tx] = (__bf16)tile[tx][ty+rr*8];
}

// out_proj K-concat transpose: [layer][dir][1024][512] f32 -> [layer][512][2048] bf16
__global__ __launch_bounds__(256) void transpose_outw_kernel(
    const float* __restrict__ in, __bf16* __restrict__ out)
{
  __shared__ float tile[32][33];
  int z = blockIdx.z, layer = z>>1, dir = z&1;
  int n0 = blockIdx.x*32, k0 = blockIdx.y*32;
  int tx = threadIdx.x, ty = threadIdx.y;
  const float* ip = in + (size_t)z*1024*512;
  #pragma unroll
  for(int rr=0;rr<4;rr++)
    tile[ty+rr*8][tx] = ip[(size_t)(k0+ty+rr*8)*512 + n0+tx];
  __syncthreads();
  __bf16* op = out + (size_t)layer*512*2048 + (size_t)dir*1024;
  #pragma unroll
  for(int rr=0;rr<4;rr++)
    op[(size_t)(n0+ty+rr*8)*2048 + k0+tx] = (__bf16)tile[tx][ty+rr*8];
}

// ---------------------------------------------------------------------------
__global__ __launch_bounds__(256) void bn_patchify_kernel(
    const float* __restrict__ x, const float* __restrict__ bng,
    const float* __restrict__ bnb, const float* __restrict__ bnm,
    const float* __restrict__ bnv, __bf16* __restrict__ Abuf)
{
  int idx = blockIdx.x*256 + threadIdx.x;
  int row = idx / KPAD, k = idx % KPAD;
  int b = row >> 4, l = row & 15;
  float v = 0.f;
  if(k < C_IN*PATCH){
    int c = k / PATCH, j = k % PATCH;
    float xv = x[(b*C_IN + c)*TT + l*PATCH + j];
    v = (xv - bnm[c]) * rsqrtf(bnv[c] + EPS) * bng[c] + bnb[c];
  }
  Abuf[idx] = (__bf16)v;
}

__global__ __launch_bounds__(256) void cast_pad_pw_kernel(
    const float* __restrict__ pw, __bf16* __restrict__ pwb)
{
  int idx = blockIdx.x*256 + threadIdx.x;
  if(idx >= 512*KPAD) return;
  int n = idx / KPAD, k = idx % KPAD;
  pwb[idx] = (__bf16)(k < C_IN*PATCH ? pw[n*(C_IN*PATCH) + k] : 0.f);
}

// split-K reduce: part[dir][4][4096][64] f32 -> projb[dir][4096][64] bf16
__global__ __launch_bounds__(256) void reduce_proj_kernel(
    const float* __restrict__ part, __bf16* __restrict__ projb)
{
  int idx = blockIdx.x*256 + threadIdx.x;     // over 2*4096*64
  int dir = idx / (NROWS*64);
  int rem = idx - dir*(NROWS*64);
  const float* p0 = part + (size_t)dir*4*NROWS*64 + rem;
  float s = p0[0] + p0[(size_t)NROWS*64] + p0[(size_t)2*NROWS*64] + p0[(size_t)3*NROWS*64];
  projb[idx] = (__bf16)s;
}

// ---------------------------------------------------------------------------
// Generic MFMA bf16 GEMM (swapped-operand epilogue). EPI: 0 plain f32 (ACC=1
// read-modify-write, ACC=2 atomicAdd); 1 dual f32+bf16; 2 bf16 softplus+bias;
// 3 bf16-only. Batched over blockIdx.z with element strides sA/sB/sC/sBias.
// ---------------------------------------------------------------------------
template<int BM, int BN, int BK, int ACC, int EPI>
__global__ __launch_bounds__(256) void mfma_gemm(
    const __bf16* __restrict__ A, const __bf16* __restrict__ Bt,
    float* __restrict__ C, __bf16* __restrict__ Cb,
    const float* __restrict__ bias, int N, int K, int lda, int ldb,
    size_t sA, size_t sB, size_t sC, size_t sBias)
{
  constexpr int NGA = BM/16, NGB = BN/16;
  constexpr int APW = NGA/4, BPW = NGB/4;
  constexpr int MI  = BM/32, FN  = BN/32;
  constexpr int NSL = BK/32;
  __shared__ __align__(16) __bf16 As[NSL*NGA*512];
  __shared__ __align__(16) __bf16 Bs[NSL*NGB*512];
  int z = blockIdx.z;
  A  += (size_t)z*sA;  Bt += (size_t)z*sB;
  if(EPI==0 || EPI==1) C  += (size_t)z*sC;
  if(EPI!=0)           Cb += (size_t)z*sC;
  if(EPI==2)           bias += (size_t)z*sBias;
  int tid  = threadIdx.x;
  int lane = tid & 63, w = tid >> 6;
  int wrow = w >> 1, wcol = w & 1;
  int r = lane & 15, q = lane >> 4;
  int row0 = blockIdx.y*BM, col0 = blockIdx.x*BN;

  f32x4 acc[MI][FN];
  #pragma unroll
  for(int i=0;i<MI;i++)
    #pragma unroll
    for(int j=0;j<FN;j++) acc[i][j] = (f32x4)0.f;

  const __bf16* aSrc[APW];
  #pragma unroll
  for(int g=0;g<APW;g++)
    aSrc[g] = A + (size_t)(row0 + (w*APW+g)*16 + r)*lda + q*8;
  const __bf16* bSrc[BPW];
  #pragma unroll
  for(int g=0;g<BPW;g++)
    bSrc[g] = Bt + (size_t)(col0 + (w*BPW+g)*16 + r)*ldb + q*8;

  for(int k0=0;k0<K;k0+=BK){
    #pragma unroll
    for(int s=0;s<NSL;s++){
      #pragma unroll
      for(int g=0;g<APW;g++)
        gload_lds16(aSrc[g] + k0 + s*32, As + (s*NGA + w*APW+g)*512);
      #pragma unroll
      for(int g=0;g<BPW;g++)
        gload_lds16(bSrc[g] + k0 + s*32, Bs + (s*NGB + w*BPW+g)*512);
    }
    __syncthreads();
    #pragma unroll
    for(int s=0;s<NSL;s++){
      bf16x8 aF[MI], bF[FN];
      #pragma unroll
      for(int i=0;i<MI;i++)
        aF[i] = *(const bf16x8*)(As + (s*NGA + wrow*MI+i)*512 + lane*8);
      #pragma unroll
      for(int j=0;j<FN;j++)
        bF[j] = *(const bf16x8*)(Bs + (s*NGB + wcol*FN+j)*512 + lane*8);
      #pragma unroll
      for(int i=0;i<MI;i++)
        #pragma unroll
        for(int j=0;j<FN;j++)
          acc[i][j] = __builtin_amdgcn_mfma_f32_16x16x32_bf16(bF[j], aF[i], acc[i][j], 0, 0, 0);
    }
    __syncthreads();
  }

  #pragma unroll
  for(int i=0;i<MI;i++){
    int m = row0 + wrow*(BM/2) + i*16 + r;
    #pragma unroll
    for(int j=0;j<FN;j++){
      int n = col0 + wcol*(BN/2) + j*16 + q*4;
      if(EPI==2){
        const float* bp = bias + n;
        bf16x4 hv;
        #pragma unroll
        for(int p=0;p<4;p++) hv[p] = (__bf16)softplusf(acc[i][j][p] + bp[p]);
        *(bf16x4*)(Cb + (size_t)m*N + n) = hv;
      } else if(EPI==3){
        bf16x4 hv;
        #pragma unroll
        for(int p=0;p<4;p++) hv[p] = (__bf16)acc[i][j][p];
        *(bf16x4*)(Cb + (size_t)m*N + n) = hv;
      } else {
        float* cp = C + (size_t)m*N + n;
        if(ACC==2){
          #pragma unroll
          for(int p=0;p<4;p++) atomicAdd(cp + p, acc[i][j][p]);
        } else {
          f32x4 ov = acc[i][j];
          if(ACC==1){
            f32x4 cv = *(const f32x4*)cp;
            #pragma unroll
            for(int p=0;p<4;p++) ov[p] += cv[p];
          }
          *(f32x4*)cp = ov;
          if(EPI==1){
            bf16x4 hv;
            #pragma unroll
            for(int p=0;p<4;p++) hv[p] = (__bf16)ov[p];
            *(bf16x4*)(Cb + (size_t)m*N + n) = hv;
          }
        }
      }
    }
  }
}

// ---------------------------------------------------------------------------
// in_proj GEMM (R8 form — empirical 59 µs floor). Both dirs N-concat
// (M=4096, N=4096, K=512), BM=128, BN=64, BK=64, grid 64x32, XCD swizzle.
// Fused conv(4)+SiLU epilogue via lane shuffles. Outputs token order bf16.
// ---------------------------------------------------------------------------
__global__ __launch_bounds__(256, 3) void mfma_inproj_conv(
    const __bf16* __restrict__ A, const __bf16* __restrict__ Bt,
    const float* __restrict__ cw, const float* __restrict__ cb,
    __bf16* __restrict__ ucb, __bf16* __restrict__ szb)
{
  constexpr int LDA = 512, LDB = 512, K = 512;
  __shared__ __align__(16) __bf16 As[2*8*512];    // 16 KB
  __shared__ __align__(16) __bf16 Bs[2*4*512];    // 8 KB
  __shared__ float4 s_w4[64];
  __shared__ float  s_b[64];
  int tid  = threadIdx.x;
  int lane = tid & 63, w = tid >> 6;
  int wrow = w >> 1, wcol = w & 1;
  int r = lane & 15, q = lane >> 4;

  int lin  = blockIdx.x + gridDim.x*blockIdx.y;   // gridDim.x = 64
  int xcd  = lin & 7;
  int idx  = lin >> 3;
  int colb = xcd*8 + (idx & 7);
  int rowb = idx >> 3;
  int row0 = rowb*128, col0 = colb*64;

  int dirq = col0 >> 11;
  int feat0 = col0 & 2047;
  bool is_u = feat0 < 1024;
  int dblk = col0 & 1023;
  if(is_u && tid < 64){
    s_w4[tid] = ((const float4*)(cw + dirq*4096))[dblk + tid];
    s_b[tid]  = (cb + dirq*1024)[dblk + tid];
  }

  f32x4 acc[4][2];
  #pragma unroll
  for(int i=0;i<4;i++)
    #pragma unroll
    for(int j=0;j<2;j++) acc[i][j] = (f32x4)0.f;

  const __bf16* aSrc[2];
  #pragma unroll
  for(int g=0;g<2;g++)
    aSrc[g] = A + (size_t)(row0 + (w*2+g)*16 + r)*LDA + q*8;
  const __bf16* bSrc0 = Bt + (size_t)(col0 + w*16 + r)*LDB + q*8;

  for(int k0=0;k0<K;k0+=64){
    #pragma unroll
    for(int s=0;s<2;s++){
      #pragma unroll
      for(int g=0;g<2;g++)
        gload_lds16(aSrc[g] + k0 + s*32, As + (s*8 + w*2+g)*512);
      gload_lds16(bSrc0 + k0 + s*32, Bs + (s*4 + w)*512);
    }
    __syncthreads();
    #pragma unroll
    for(int s=0;s<2;s++){
      bf16x8 aF[4], bF[2];
      #pragma unroll
      for(int i=0;i<4;i++)
        aF[i] = *(const bf16x8*)(As + (s*8 + wrow*4+i)*512 + lane*8);
      #pragma unroll
      for(int j=0;j<2;j++)
        bF[j] = *(const bf16x8*)(Bs + (s*4 + wcol*2+j)*512 + lane*8);
      #pragma unroll
      for(int i=0;i<4;i++)
        #pragma unroll
        for(int j=0;j<2;j++)
          acc[i][j] = __builtin_amdgcn_mfma_f32_16x16x32_bf16(bF[j], aF[i], acc[i][j], 0, 0, 0);
    }
    __syncthreads();
  }

  __bf16* ucbD = ucb + (size_t)dirq*NROWS*1024;
  __bf16* szD  = szb + (size_t)dirq*NROWS*1024;

  #pragma unroll
  for(int i=0;i<4;i++){
    int tok = row0 + wrow*64 + i*16 + r;
    #pragma unroll
    for(int j=0;j<2;j++){
      int nloc = wcol*32 + j*16 + q*4;
      if(is_u){
        int f = nloc;
        int d = dblk + f;
        float vout[4];
        if(dirq==0){
          #pragma unroll
          for(int p=0;p<4;p++){
            float cur = acc[i][j][p];
            float m1 = __shfl_up(cur, 1, 64);
            float m2 = __shfl_up(cur, 2, 64);
            float m3 = __shfl_up(cur, 3, 64);
            float4 w4 = s_w4[f+p];
            float v = s_b[f+p] + w4.w*cur;
            v += (r>=1)? w4.z*m1 : 0.f;
            v += (r>=2)? w4.y*m2 : 0.f;
            v += (r>=3)? w4.x*m3 : 0.f;
            vout[p] = v;
          }
        } else {
          #pragma unroll
          for(int p=0;p<4;p++){
            float cur = acc[i][j][p];
            float p1 = __shfl_down(cur, 1, 64);
            float p2 = __shfl_down(cur, 2, 64);
            float p3 = __shfl_down(cur, 3, 64);
            float4 w4 = s_w4[f+p];
            float v = s_b[f+p] + w4.w*cur;
            v += (r<=14)? w4.z*p1 : 0.f;
            v += (r<=13)? w4.y*p2 : 0.f;
            v += (r<=12)? w4.x*p3 : 0.f;
            vout[p] = v;
          }
        }
        bf16x4 hv;
        #pragma unroll
        for(int p=0;p<4;p++) hv[p] = (__bf16)siluf(vout[p]);
        *(bf16x4*)(ucbD + (size_t)tok*1024 + d) = hv;
      } else {
        int dz = feat0 - 1024 + nloc;
        bf16x4 hv;
        #pragma unroll
        for(int p=0;p<4;p++) hv[p] = (__bf16)siluf(acc[i][j][p]);
        *(bf16x4*)(szD + (size_t)tok*1024 + dz) = hv;
      }
    }
  }
}

// ---------------------------------------------------------------------------
__global__ __launch_bounds__(256) void ln_pos_kernel(
    const float* __restrict__ in, const float* __restrict__ pb,
    const float* __restrict__ g, const float* __restrict__ bt,
    const float* __restrict__ pos, float* __restrict__ out)
{
  __shared__ float sred[4];
  int row = blockIdx.x; int l = row & 15; int tid = threadIdx.x;
  const float* ip = in + (size_t)row*512;
  float v0 = ip[tid] + pb[tid], v1 = ip[tid+256] + pb[tid+256];
  float s = block_reduce_sum(v0+v1, sred);
  float mean = s * (1.f/512.f);
  float d0 = v0-mean, d1 = v1-mean;
  float vs = block_reduce_sum(d0*d0+d1*d1, sred);
  float rstd = rsqrtf(vs*(1.f/512.f) + EPS);
  out[(size_t)row*512+tid]     = d0*rstd*g[tid]     + bt[tid]     + pos[l*512+tid];
  out[(size_t)row*512+tid+256] = d1*rstd*g[tid+256] + bt[tid+256] + pos[l*512+tid+256];
}

__global__ __launch_bounds__(256) void ln_bf16_kernel(
    const float* __restrict__ in, const float* __restrict__ g,
    const float* __restrict__ bt, __bf16* __restrict__ out)
{
  __shared__ float sred[4];
  int row = blockIdx.x; int tid = threadIdx.x;
  const float* ip = in + (size_t)row*512;
  float v0 = ip[tid], v1 = ip[tid+256];
  float s = block_reduce_sum(v0+v1, sred);
  float mean = s * (1.f/512.f);
  float d0 = v0-mean, d1 = v1-mean;
  float vs = block_reduce_sum(d0*d0+d1*d1, sred);
  float rstd = rsqrtf(vs*(1.f/512.f) + EPS);
  out[(size_t)row*512+tid]     = (__bf16)(d0*rstd*g[tid]     + bt[tid]);
  out[(size_t)row*512+tid+256] = (__bf16)(d1*rstd*g[tid+256] + bt[tid+256]);
}

__global__ __launch_bounds__(256) void ln_f32_kernel(
    const float* __restrict__ in, const float* __restrict__ g,
    const float* __restrict__ bt, float* __restrict__ out)
{
  __shared__ float sred[4];
  int row = blockIdx.x; int tid = threadIdx.x;
  const float* ip = in + (size_t)row*512;
  float v0 = ip[tid], v1 = ip[tid+256];
  float s = block_reduce_sum(v0+v1, sred);
  float mean = s * (1.f/512.f);
  float d0 = v0-mean, d1 = v1-mean;
  float vs = block_reduce_sum(d0*d0+d1*d1, sred);
  float rstd = rsqrtf(vs*(1.f/512.f) + EPS);
  out[(size_t)row*512+tid]     = d0*rstd*g[tid]     + bt[tid];
  out[(size_t)row*512+tid+256] = d1*rstd*g[tid+256] + bt[tid+256];
}

// ---------------------------------------------------------------------------
// selective scan, both dirs (gridDim.y=8: dir = y>>2). dt/uc/sz/proj bf16,
// token order. gb out: [row][2048] bf16 K-concat for out_proj.
// ---------------------------------------------------------------------------
__global__ __launch_bounds__(256) void scan_kernel(
    const __bf16* __restrict__ dtb, const __bf16* __restrict__ ucb,
    const __bf16* __restrict__ projb, const __bf16* __restrict__ szb,
    const float* __restrict__ A_log, const float* __restrict__ Dskip,
    __bf16* __restrict__ gb)
{
  int b = blockIdx.x;
  int dirq = blockIdx.y >> 2;
  int d = (blockIdx.y & 3)*256 + threadIdx.x;
  const __bf16* dtp = dtb + (size_t)dirq*NROWS*1024;
  const __bf16* ucp = ucb + (size_t)dirq*NROWS*1024;
  const __bf16* prp = projb + (size_t)dirq*NROWS*64;
  const __bf16* szp = szb  + (size_t)dirq*NROWS*1024;
  const float*  Alp = A_log + (size_t)dirq*1024*16;
  float Dv = Dskip[dirq*1024 + d];
  __shared__ float sB[16][16], sC[16][16];
  {
    int s = threadIdx.x >> 4, n = threadIdx.x & 15;
    int tok = dirq ? 15-s : s;
    sB[s][n] = (float)prp[(size_t)(b*16+tok)*64 + 32 + n];
    sC[s][n] = (float)prp[(size_t)(b*16+tok)*64 + 48 + n];
  }
  __syncthreads();
  float a[16], hst[16];
  #pragma unroll
  for(int n=0;n<16;n++){ a[n] = -__expf(Alp[d*16+n]); hst[n]=0.f; }
  for(int s=0;s<16;s++){
    int tok = dirq ? 15-s : s;
    size_t o = (size_t)(b*16+tok)*1024 + d;
    float dtv = (float)dtp[o];
    float ucv = (float)ucp[o];
    float dtu = dtv*ucv;
    float y = 0.f;
    #pragma unroll
    for(int n=0;n<16;n++){
      hst[n] = __expf(dtv*a[n])*hst[n] + dtu*sB[s][n];
      y += hst[n]*sC[s][n];
    }
    float zs = (float)szp[o];
    gb[(size_t)(b*16+tok)*2048 + dirq*1024 + d] = (__bf16)((y + ucv*Dv) * zs);
  }
}

// ---------------------------------------------------------------------------
extern "C" void kernel_launch(void* const* d_in, const int* in_sizes, int n_in,
                              void* d_out, int out_size, void* d_ws, size_t ws_size,
                              hipStream_t stream) {
  (void)in_sizes; (void)n_in; (void)out_size; (void)ws_size;
  const float* x         = (const float*)d_in[0];
  const float* bn_gamma  = (const float*)d_in[1];
  const float* bn_beta   = (const float*)d_in[2];
  const float* bn_mean   = (const float*)d_in[3];
  const float* bn_var    = (const float*)d_in[4];
  const float* patch_w   = (const float*)d_in[5];
  const float* patch_b   = (const float*)d_in[6];
  const float* ln_pg     = (const float*)d_in[7];
  const float* ln_pb     = (const float*)d_in[8];
  const float* pos       = (const float*)d_in[9];
  const float* blk_ln_g  = (const float*)d_in[10];
  const float* blk_ln_b  = (const float*)d_in[11];
  const float* in_proj_w = (const float*)d_in[12];
  const float* conv_w    = (const float*)d_in[13];
  const float* conv_b    = (const float*)d_in[14];
  const float* x_proj_w  = (const float*)d_in[15];
  const float* dt_proj_w = (const float*)d_in[16];
  const float* dt_proj_b = (const float*)d_in[17];
  const float* A_log     = (const float*)d_in[18];
  const float* Dskip     = (const float*)d_in[19];
  const float* out_proj_w= (const float*)d_in[20];
  const float* fin_g     = (const float*)d_in[21];
  const float* fin_b     = (const float*)d_in[22];

  char* p = (char*)d_ws;
  float*  h     = (float*)p;  p += (size_t)NROWS*512*4;      // 8 MB
  float*  projP = (float*)p;  p += (size_t)2*4*NROWS*64*4;   // 8 MB (split-K parts)
  __bf16* hnb   = (__bf16*)p; p += (size_t)NROWS*512*2;      // 4 MB
  __bf16* ucb2  = (__bf16*)p; p += (size_t)2*NROWS*1024*2;   // 16 MB
  __bf16* szb2  = (__bf16*)p; p += (size_t)2*NROWS*1024*2;   // 16 MB
  __bf16* dtb2  = (__bf16*)p; p += (size_t)2*NROWS*1024*2;   // 16 MB
  __bf16* gbK   = (__bf16*)p; p += (size_t)NROWS*2048*2;     // 16 MB (patch f32 scratch too)
  __bf16* projb2=(__bf16*)p;  p += (size_t)2*NROWS*64*2;     // 1 MB
  __bf16* wtin  = (__bf16*)p; p += (size_t)4*2048*512*2;     // 8 MB
  __bf16* wtoutK=(__bf16*)p;  p += (size_t)2*512*2048*2;     // 4 MB
  __bf16* wtx   = (__bf16*)p; p += (size_t)4*64*1024*2;      // 0.5 MB
  __bf16* wdtT  = (__bf16*)p; p += (size_t)4*1024*32*2;      // 0.25 MB
  __bf16* Abuf  = (__bf16*)p; p += (size_t)NROWS*KPAD*2;     // 0.75 MB
  __bf16* pwb   = (__bf16*)p; p += (size_t)512*KPAD*2;       // 96 KB

  // ---- weight prep ----
  transpose_bf16_kernel<<<dim3(64, 16, 4), dim3(32,8), 0, stream>>>(
      in_proj_w, wtin, 512, 2048);
  transpose_outw_kernel<<<dim3(16, 32, 4), dim3(32,8), 0, stream>>>(
      out_proj_w, wtoutK);
  transpose_bf16_kernel<<<dim3(2, 32, 4), dim3(32,8), 0, stream>>>(
      x_proj_w, wtx, 1024, 64);
  transpose_bf16_kernel<<<dim3(32, 1, 4), dim3(32,8), 0, stream>>>(
      dt_proj_w, wdtT, 32, 1024);
  cast_pad_pw_kernel<<<(512*KPAD + 255)/256, 256, 0, stream>>>(patch_w, pwb);

  // ---- patch embed ----
  bn_patchify_kernel<<<(NROWS*KPAD)/256, 256, 0, stream>>>(
      x, bn_gamma, bn_beta, bn_mean, bn_var, Abuf);
  mfma_gemm<128,128,32,0,0><<<dim3(4, 32, 1), 256, 0, stream>>>(
      Abuf, pwb, (float*)gbK, nullptr, nullptr, 512, KPAD, KPAD, KPAD, 0,0,0,0);
  ln_pos_kernel<<<NROWS, 256, 0, stream>>>((float*)gbK, patch_b, ln_pg, ln_pb, pos, h);

  for(int i=0;i<2;i++){
    ln_bf16_kernel<<<NROWS, 256, 0, stream>>>(h, blk_ln_g + i*512, blk_ln_b + i*512, hnb);
    // in_proj both dirs + conv + silu -> ucb2/szb2 (bf16, token order)
    mfma_inproj_conv<<<dim3(64, 32), 256, 0, stream>>>(
        hnb, wtin + (size_t)i*4096*512, conv_w + (size_t)i*2*4096,
        conv_b + (size_t)i*2*1024, ucb2, szb2);
    // x_proj split-K=4 per dir -> projP parts (f32), then reduce -> projb bf16
    for(int dir=0;dir<2;dir++){
      mfma_gemm<64,64,64,0,0><<<dim3(1, 64, 4), 256, 0, stream>>>(
          ucb2 + (size_t)dir*NROWS*1024,
          wtx + (size_t)(i*2+dir)*64*1024,
          projP + (size_t)dir*4*NROWS*64, nullptr, nullptr,
          64, 256, 1024, 1024,
          256, 256, (size_t)NROWS*64, 0);
    }
    reduce_proj_kernel<<<(2*NROWS*64)/256, 256, 0, stream>>>(projP, projb2);
    // dt = softplus(dtr @ Wdt + bias) -> bf16
    mfma_gemm<64,64,32,0,2><<<dim3(16, 64, 2), 256, 0, stream>>>(
        projb2, wdtT + (size_t)i*2*1024*32, nullptr, dtb2, dt_proj_b + (size_t)i*2*1024,
        1024, 32, 64, 32,
        (size_t)NROWS*64, (size_t)1024*32, (size_t)NROWS*1024, 1024);
    // scan both dirs -> gbK [row][2048]
    scan_kernel<<<dim3(BB, 8), 256, 0, stream>>>(
        dtb2, ucb2, projb2, szb2, A_log + (size_t)i*2*1024*16,
        Dskip + (size_t)i*2*1024, gbK);
    // out_proj split-K=4, atomicAdd f32 into h (h holds residual)
    mfma_gemm<64,64,64,2,0><<<dim3(8, 64, 4), 256, 0, stream>>>(
        gbK, wtoutK + (size_t)i*512*2048, h, nullptr, nullptr,
        512, 512, 2048, 2048,
        512, 512, 0, 0);
  }
  ln_f32_kernel<<<NROWS, 256, 0, stream>>>(h, fin_g, fin_b, (float*)d_out);
}

// Round 11
// 493.422 us; speedup vs baseline: 1.3304x; 1.3304x over previous
//
#include <hip/hip_runtime.h>
#include <math.h>
#include <stdint.h>

#define BB 256
#define C_IN 7
#define TT 160
#define PATCH 10
#define D_MODEL 512
#define L_TOK 16
#define D_INNER 1024
#define D_STATE 16
#define DT_RANK 32
#define EPS 1e-5f
#define NROWS (BB*L_TOK)   // 4096
#define KPAD 96            // 70 padded to 3*32

typedef __bf16 bf16x8 __attribute__((ext_vector_type(8)));
typedef __bf16 bf16x4 __attribute__((ext_vector_type(4)));
typedef float  f32x4  __attribute__((ext_vector_type(4)));

__device__ __forceinline__ float siluf(float x){ return x / (1.f + __expf(-x)); }
__device__ __forceinline__ float softplusf(float x){ return (x > 20.f) ? x : log1pf(__expf(x)); }

__device__ __forceinline__ void gload_lds16(const void* gp, void* lp){
  __builtin_amdgcn_global_load_lds(
      (const __attribute__((address_space(1))) unsigned int*)(uintptr_t)gp,
      (__attribute__((address_space(3))) unsigned int*)(uintptr_t)lp, 16, 0, 0);
}

__device__ __forceinline__ float block_reduce_sum(float v, float* sred4){
  for(int off=32; off>0; off>>=1) v += __shfl_down(v, off, 64);
  int lane = threadIdx.x & 63, wid = threadIdx.x >> 6;
  if(lane==0) sred4[wid] = v;
  __syncthreads();
  if(threadIdx.x==0) sred4[0] = sred4[0]+sred4[1]+sred4[2]+sred4[3];
  __syncthreads();
  float r = sred4[0];
  __syncthreads();
  return r;
}

// ---------------------------------------------------------------------------
// transpose + fp32->bf16: in [z][K][N] f32 -> out [z][N][K] bf16
// ---------------------------------------------------------------------------
__global__ __launch_bounds__(256) void transpose_bf16_kernel(
    const float* __restrict__ in, __bf16* __restrict__ out, int K, int N)
{
  __shared__ float tile[32][33];
  size_t moff = (size_t)blockIdx.z * K * N;
  int n0 = blockIdx.x*32, k0 = blockIdx.y*32;
  int tx = threadIdx.x, ty = threadIdx.y;
  #pragma unroll
  for(int rr=0;rr<4;rr++)
    tile[ty+rr*8][tx] = in[moff + (size_t)(k0+ty+rr*8)*N + n0+tx];
  __syncthreads();
  #pragma unroll
  for(int rr=0;rr<4;rr++)
    out[moff + (size_t)(n0+ty+rr*8)*K + k0+tx] = (__bf16)tile[tx][ty+rr*8];
}

// out_proj K-concat transpose: [layer][dir][1024][512] f32 -> [layer][512][2048] bf16
__global__ __launch_bounds__(256) void transpose_outw_kernel(
    const float* __restrict__ in, __bf16* __restrict__ out)
{
  __shared__ float tile[32][33];
  int z = blockIdx.z, layer = z>>1, dir = z&1;
  int n0 = blockIdx.x*32, k0 = blockIdx.y*32;
  int tx = threadIdx.x, ty = threadIdx.y;
  const float* ip = in + (size_t)z*1024*512;
  #pragma unroll
  for(int rr=0;rr<4;rr++)
    tile[ty+rr*8][tx] = ip[(size_t)(k0+ty+rr*8)*512 + n0+tx];
  __syncthreads();
  __bf16* op = out + (size_t)layer*512*2048 + (size_t)dir*1024;
  #pragma unroll
  for(int rr=0;rr<4;rr++)
    op[(size_t)(n0+ty+rr*8)*2048 + k0+tx] = (__bf16)tile[tx][ty+rr*8];
}

// ---------------------------------------------------------------------------
__global__ __launch_bounds__(256) void bn_patchify_kernel(
    const float* __restrict__ x, const float* __restrict__ bng,
    const float* __restrict__ bnb, const float* __restrict__ bnm,
    const float* __restrict__ bnv, __bf16* __restrict__ Abuf)
{
  int idx = blockIdx.x*256 + threadIdx.x;
  int row = idx / KPAD, k = idx % KPAD;
  int b = row >> 4, l = row & 15;
  float v = 0.f;
  if(k < C_IN*PATCH){
    int c = k / PATCH, j = k % PATCH;
    float xv = x[(b*C_IN + c)*TT + l*PATCH + j];
    v = (xv - bnm[c]) * rsqrtf(bnv[c] + EPS) * bng[c] + bnb[c];
  }
  Abuf[idx] = (__bf16)v;
}

__global__ __launch_bounds__(256) void cast_pad_pw_kernel(
    const float* __restrict__ pw, __bf16* __restrict__ pwb)
{
  int idx = blockIdx.x*256 + threadIdx.x;
  if(idx >= 512*KPAD) return;
  int n = idx / KPAD, k = idx % KPAD;
  pwb[idx] = (__bf16)(k < C_IN*PATCH ? pw[n*(C_IN*PATCH) + k] : 0.f);
}

// split-K reduce: part[dir][4][4096][64] f32 -> projb[dir][4096][64] bf16
__global__ __launch_bounds__(256) void reduce_proj_kernel(
    const float* __restrict__ part, __bf16* __restrict__ projb)
{
  int idx = blockIdx.x*256 + threadIdx.x;     // over 2*4096*64
  int dir = idx / (NROWS*64);
  int rem = idx - dir*(NROWS*64);
  const float* p0 = part + (size_t)dir*4*NROWS*64 + rem;
  float s = p0[0] + p0[(size_t)NROWS*64] + p0[(size_t)2*NROWS*64] + p0[(size_t)3*NROWS*64];
  projb[idx] = (__bf16)s;
}

// ---------------------------------------------------------------------------
// out_proj parts reduce + residual + LayerNorm, one row per block.
// h += sum_{ks<4} parts[ks][row]; then LN(h)*g+bt -> bf16 hnb (FINAL=0) or
// f32 out (FINAL=1).
// ---------------------------------------------------------------------------
template<int FINAL>
__global__ __launch_bounds__(256) void reduce_ln_kernel(
    const float* __restrict__ parts, float* __restrict__ h,
    const float* __restrict__ g, const float* __restrict__ bt,
    float* __restrict__ outf, __bf16* __restrict__ outb)
{
  __shared__ float sred[4];
  int row = blockIdx.x; int tid = threadIdx.x;
  size_t o0 = (size_t)row*512 + tid, o1 = o0 + 256;
  float v0 = h[o0], v1 = h[o1];
  #pragma unroll
  for(int ks=0;ks<4;ks++){
    v0 += parts[(size_t)ks*NROWS*512 + o0];
    v1 += parts[(size_t)ks*NROWS*512 + o1];
  }
  h[o0] = v0; h[o1] = v1;
  float s = block_reduce_sum(v0+v1, sred);
  float mean = s * (1.f/512.f);
  float d0 = v0-mean, d1 = v1-mean;
  float vs = block_reduce_sum(d0*d0+d1*d1, sred);
  float rstd = rsqrtf(vs*(1.f/512.f) + EPS);
  float r0 = d0*rstd*g[tid]     + bt[tid];
  float r1 = d1*rstd*g[tid+256] + bt[tid+256];
  if(FINAL){ outf[o0] = r0; outf[o1] = r1; }
  else     { outb[o0] = (__bf16)r0; outb[o1] = (__bf16)r1; }
}

// ---------------------------------------------------------------------------
// Generic MFMA bf16 GEMM (swapped-operand epilogue). EPI: 0 plain f32;
// 2 bf16 softplus+bias; 3 bf16-only. z decomposition: zi = z % ZDIV (inner,
// strides sA/sB/sC), zo = z / ZDIV (outer, strides sAo/sBo/sCo; bias zo*sBias).
// ---------------------------------------------------------------------------
template<int BM, int BN, int BK, int ZDIV, int EPI>
__global__ __launch_bounds__(256) void mfma_gemm(
    const __bf16* __restrict__ A, const __bf16* __restrict__ Bt,
    float* __restrict__ C, __bf16* __restrict__ Cb,
    const float* __restrict__ bias, int N, int K, int lda, int ldb,
    size_t sA, size_t sB, size_t sC,
    size_t sAo, size_t sBo, size_t sCo, size_t sBias)
{
  constexpr int NGA = BM/16, NGB = BN/16;
  constexpr int APW = NGA/4, BPW = NGB/4;
  constexpr int MI  = BM/32, FN  = BN/32;
  constexpr int NSL = BK/32;
  __shared__ __align__(16) __bf16 As[NSL*NGA*512];
  __shared__ __align__(16) __bf16 Bs[NSL*NGB*512];
  int z = blockIdx.z;
  int zi = z % ZDIV, zo = z / ZDIV;
  A  += (size_t)zi*sA + (size_t)zo*sAo;
  Bt += (size_t)zi*sB + (size_t)zo*sBo;
  if(EPI==0) C  += (size_t)zi*sC + (size_t)zo*sCo;
  else       Cb += (size_t)zi*sC + (size_t)zo*sCo;
  if(EPI==2) bias += (size_t)zo*sBias;
  int tid  = threadIdx.x;
  int lane = tid & 63, w = tid >> 6;
  int wrow = w >> 1, wcol = w & 1;
  int r = lane & 15, q = lane >> 4;
  int row0 = blockIdx.y*BM, col0 = blockIdx.x*BN;

  f32x4 acc[MI][FN];
  #pragma unroll
  for(int i=0;i<MI;i++)
    #pragma unroll
    for(int j=0;j<FN;j++) acc[i][j] = (f32x4)0.f;

  const __bf16* aSrc[APW];
  #pragma unroll
  for(int g=0;g<APW;g++)
    aSrc[g] = A + (size_t)(row0 + (w*APW+g)*16 + r)*lda + q*8;
  const __bf16* bSrc[BPW];
  #pragma unroll
  for(int g=0;g<BPW;g++)
    bSrc[g] = Bt + (size_t)(col0 + (w*BPW+g)*16 + r)*ldb + q*8;

  for(int k0=0;k0<K;k0+=BK){
    #pragma unroll
    for(int s=0;s<NSL;s++){
      #pragma unroll
      for(int g=0;g<APW;g++)
        gload_lds16(aSrc[g] + k0 + s*32, As + (s*NGA + w*APW+g)*512);
      #pragma unroll
      for(int g=0;g<BPW;g++)
        gload_lds16(bSrc[g] + k0 + s*32, Bs + (s*NGB + w*BPW+g)*512);
    }
    __syncthreads();
    #pragma unroll
    for(int s=0;s<NSL;s++){
      bf16x8 aF[MI], bF[FN];
      #pragma unroll
      for(int i=0;i<MI;i++)
        aF[i] = *(const bf16x8*)(As + (s*NGA + wrow*MI+i)*512 + lane*8);
      #pragma unroll
      for(int j=0;j<FN;j++)
        bF[j] = *(const bf16x8*)(Bs + (s*NGB + wcol*FN+j)*512 + lane*8);
      #pragma unroll
      for(int i=0;i<MI;i++)
        #pragma unroll
        for(int j=0;j<FN;j++)
          acc[i][j] = __builtin_amdgcn_mfma_f32_16x16x32_bf16(bF[j], aF[i], acc[i][j], 0, 0, 0);
    }
    __syncthreads();
  }

  #pragma unroll
  for(int i=0;i<MI;i++){
    int m = row0 + wrow*(BM/2) + i*16 + r;
    #pragma unroll
    for(int j=0;j<FN;j++){
      int n = col0 + wcol*(BN/2) + j*16 + q*4;
      if(EPI==2){
        const float* bp = bias + n;
        bf16x4 hv;
        #pragma unroll
        for(int p=0;p<4;p++) hv[p] = (__bf16)softplusf(acc[i][j][p] + bp[p]);
        *(bf16x4*)(Cb + (size_t)m*N + n) = hv;
      } else if(EPI==3){
        bf16x4 hv;
        #pragma unroll
        for(int p=0;p<4;p++) hv[p] = (__bf16)acc[i][j][p];
        *(bf16x4*)(Cb + (size_t)m*N + n) = hv;
      } else {
        *(f32x4*)(C + (size_t)m*N + n) = acc[i][j];
      }
    }
  }
}

// ---------------------------------------------------------------------------
// in_proj GEMM (R8 form — empirical 59 µs floor). Both dirs N-concat
// (M=4096, N=4096, K=512), BM=128, BN=64, BK=64, grid 64x32, XCD swizzle.
// Fused conv(4)+SiLU epilogue via lane shuffles. Outputs token order bf16.
// ---------------------------------------------------------------------------
__global__ __launch_bounds__(256, 3) void mfma_inproj_conv(
    const __bf16* __restrict__ A, const __bf16* __restrict__ Bt,
    const float* __restrict__ cw, const float* __restrict__ cb,
    __bf16* __restrict__ ucb, __bf16* __restrict__ szb)
{
  constexpr int LDA = 512, LDB = 512, K = 512;
  __shared__ __align__(16) __bf16 As[2*8*512];    // 16 KB
  __shared__ __align__(16) __bf16 Bs[2*4*512];    // 8 KB
  __shared__ float4 s_w4[64];
  __shared__ float  s_b[64];
  int tid  = threadIdx.x;
  int lane = tid & 63, w = tid >> 6;
  int wrow = w >> 1, wcol = w & 1;
  int r = lane & 15, q = lane >> 4;

  int lin  = blockIdx.x + gridDim.x*blockIdx.y;   // gridDim.x = 64
  int xcd  = lin & 7;
  int idx  = lin >> 3;
  int colb = xcd*8 + (idx & 7);
  int rowb = idx >> 3;
  int row0 = rowb*128, col0 = colb*64;

  int dirq = col0 >> 11;
  int feat0 = col0 & 2047;
  bool is_u = feat0 < 1024;
  int dblk = col0 & 1023;
  if(is_u && tid < 64){
    s_w4[tid] = ((const float4*)(cw + dirq*4096))[dblk + tid];
    s_b[tid]  = (cb + dirq*1024)[dblk + tid];
  }

  f32x4 acc[4][2];
  #pragma unroll
  for(int i=0;i<4;i++)
    #pragma unroll
    for(int j=0;j<2;j++) acc[i][j] = (f32x4)0.f;

  const __bf16* aSrc[2];
  #pragma unroll
  for(int g=0;g<2;g++)
    aSrc[g] = A + (size_t)(row0 + (w*2+g)*16 + r)*LDA + q*8;
  const __bf16* bSrc0 = Bt + (size_t)(col0 + w*16 + r)*LDB + q*8;

  for(int k0=0;k0<K;k0+=64){
    #pragma unroll
    for(int s=0;s<2;s++){
      #pragma unroll
      for(int g=0;g<2;g++)
        gload_lds16(aSrc[g] + k0 + s*32, As + (s*8 + w*2+g)*512);
      gload_lds16(bSrc0 + k0 + s*32, Bs + (s*4 + w)*512);
    }
    __syncthreads();
    #pragma unroll
    for(int s=0;s<2;s++){
      bf16x8 aF[4], bF[2];
      #pragma unroll
      for(int i=0;i<4;i++)
        aF[i] = *(const bf16x8*)(As + (s*8 + wrow*4+i)*512 + lane*8);
      #pragma unroll
      for(int j=0;j<2;j++)
        bF[j] = *(const bf16x8*)(Bs + (s*4 + wcol*2+j)*512 + lane*8);
      #pragma unroll
      for(int i=0;i<4;i++)
        #pragma unroll
        for(int j=0;j<2;j++)
          acc[i][j] = __builtin_amdgcn_mfma_f32_16x16x32_bf16(bF[j], aF[i], acc[i][j], 0, 0, 0);
    }
    __syncthreads();
  }

  __bf16* ucbD = ucb + (size_t)dirq*NROWS*1024;
  __bf16* szD  = szb + (size_t)dirq*NROWS*1024;

  #pragma unroll
  for(int i=0;i<4;i++){
    int tok = row0 + wrow*64 + i*16 + r;
    #pragma unroll
    for(int j=0;j<2;j++){
      int nloc = wcol*32 + j*16 + q*4;
      if(is_u){
        int f = nloc;
        int d = dblk + f;
        float vout[4];
        if(dirq==0){
          #pragma unroll
          for(int p=0;p<4;p++){
            float cur = acc[i][j][p];
            float m1 = __shfl_up(cur, 1, 64);
            float m2 = __shfl_up(cur, 2, 64);
            float m3 = __shfl_up(cur, 3, 64);
            float4 w4 = s_w4[f+p];
            float v = s_b[f+p] + w4.w*cur;
            v += (r>=1)? w4.z*m1 : 0.f;
            v += (r>=2)? w4.y*m2 : 0.f;
            v += (r>=3)? w4.x*m3 : 0.f;
            vout[p] = v;
          }
        } else {
          #pragma unroll
          for(int p=0;p<4;p++){
            float cur = acc[i][j][p];
            float p1 = __shfl_down(cur, 1, 64);
            float p2 = __shfl_down(cur, 2, 64);
            float p3 = __shfl_down(cur, 3, 64);
            float4 w4 = s_w4[f+p];
            float v = s_b[f+p] + w4.w*cur;
            v += (r<=14)? w4.z*p1 : 0.f;
            v += (r<=13)? w4.y*p2 : 0.f;
            v += (r<=12)? w4.x*p3 : 0.f;
            vout[p] = v;
          }
        }
        bf16x4 hv;
        #pragma unroll
        for(int p=0;p<4;p++) hv[p] = (__bf16)siluf(vout[p]);
        *(bf16x4*)(ucbD + (size_t)tok*1024 + d) = hv;
      } else {
        int dz = feat0 - 1024 + nloc;
        bf16x4 hv;
        #pragma unroll
        for(int p=0;p<4;p++) hv[p] = (__bf16)siluf(acc[i][j][p]);
        *(bf16x4*)(szD + (size_t)tok*1024 + dz) = hv;
      }
    }
  }
}

// ---------------------------------------------------------------------------
// bias + LN + pos -> h (f32), then LN(h) with layer-0 gamma/beta -> hnb bf16
// ---------------------------------------------------------------------------
__global__ __launch_bounds__(256) void ln_pos_ln_kernel(
    const float* __restrict__ in, const float* __restrict__ pb,
    const float* __restrict__ g1, const float* __restrict__ b1,
    const float* __restrict__ pos, const float* __restrict__ g2,
    const float* __restrict__ b2, float* __restrict__ h,
    __bf16* __restrict__ hnb)
{
  __shared__ float sred[4];
  int row = blockIdx.x; int l = row & 15; int tid = threadIdx.x;
  const float* ip = in + (size_t)row*512;
  float v0 = ip[tid] + pb[tid], v1 = ip[tid+256] + pb[tid+256];
  float s = block_reduce_sum(v0+v1, sred);
  float mean = s * (1.f/512.f);
  float d0 = v0-mean, d1 = v1-mean;
  float vs = block_reduce_sum(d0*d0+d1*d1, sred);
  float rstd = rsqrtf(vs*(1.f/512.f) + EPS);
  float h0 = d0*rstd*g1[tid]     + b1[tid]     + pos[l*512+tid];
  float h1 = d1*rstd*g1[tid+256] + b1[tid+256] + pos[l*512+tid+256];
  h[(size_t)row*512+tid]     = h0;
  h[(size_t)row*512+tid+256] = h1;
  // second LN
  float s2 = block_reduce_sum(h0+h1, sred);
  float mean2 = s2 * (1.f/512.f);
  float e0 = h0-mean2, e1 = h1-mean2;
  float vs2 = block_reduce_sum(e0*e0+e1*e1, sred);
  float rstd2 = rsqrtf(vs2*(1.f/512.f) + EPS);
  hnb[(size_t)row*512+tid]     = (__bf16)(e0*rstd2*g2[tid]     + b2[tid]);
  hnb[(size_t)row*512+tid+256] = (__bf16)(e1*rstd2*g2[tid+256] + b2[tid+256]);
}

// ---------------------------------------------------------------------------
// selective scan, both dirs (gridDim.y=8: dir = y>>2). dt/uc/sz/proj bf16,
// token order. gb out: [row][2048] bf16 K-concat for out_proj.
// ---------------------------------------------------------------------------
__global__ __launch_bounds__(256) void scan_kernel(
    const __bf16* __restrict__ dtb, const __bf16* __restrict__ ucb,
    const __bf16* __restrict__ projb, const __bf16* __restrict__ szb,
    const float* __restrict__ A_log, const float* __restrict__ Dskip,
    __bf16* __restrict__ gb)
{
  int b = blockIdx.x;
  int dirq = blockIdx.y >> 2;
  int d = (blockIdx.y & 3)*256 + threadIdx.x;
  const __bf16* dtp = dtb + (size_t)dirq*NROWS*1024;
  const __bf16* ucp = ucb + (size_t)dirq*NROWS*1024;
  const __bf16* prp = projb + (size_t)dirq*NROWS*64;
  const __bf16* szp = szb  + (size_t)dirq*NROWS*1024;
  const float*  Alp = A_log + (size_t)dirq*1024*16;
  float Dv = Dskip[dirq*1024 + d];
  __shared__ float sB[16][16], sC[16][16];
  {
    int s = threadIdx.x >> 4, n = threadIdx.x & 15;
    int tok = dirq ? 15-s : s;
    sB[s][n] = (float)prp[(size_t)(b*16+tok)*64 + 32 + n];
    sC[s][n] = (float)prp[(size_t)(b*16+tok)*64 + 48 + n];
  }
  __syncthreads();
  float a[16], hst[16];
  #pragma unroll
  for(int n=0;n<16;n++){ a[n] = -__expf(Alp[d*16+n]); hst[n]=0.f; }
  for(int s=0;s<16;s++){
    int tok = dirq ? 15-s : s;
    size_t o = (size_t)(b*16+tok)*1024 + d;
    float dtv = (float)dtp[o];
    float ucv = (float)ucp[o];
    float dtu = dtv*ucv;
    float y = 0.f;
    #pragma unroll
    for(int n=0;n<16;n++){
      hst[n] = __expf(dtv*a[n])*hst[n] + dtu*sB[s][n];
      y += hst[n]*sC[s][n];
    }
    float zs = (float)szp[o];
    gb[(size_t)(b*16+tok)*2048 + dirq*1024 + d] = (__bf16)((y + ucv*Dv) * zs);
  }
}

// ---------------------------------------------------------------------------
extern "C" void kernel_launch(void* const* d_in, const int* in_sizes, int n_in,
                              void* d_out, int out_size, void* d_ws, size_t ws_size,
                              hipStream_t stream) {
  (void)in_sizes; (void)n_in; (void)out_size; (void)ws_size;
  const float* x         = (const float*)d_in[0];
  const float* bn_gamma  = (const float*)d_in[1];
  const float* bn_beta   = (const float*)d_in[2];
  const float* bn_mean   = (const float*)d_in[3];
  const float* bn_var    = (const float*)d_in[4];
  const float* patch_w   = (const float*)d_in[5];
  const float* patch_b   = (const float*)d_in[6];
  const float* ln_pg     = (const float*)d_in[7];
  const float* ln_pb     = (const float*)d_in[8];
  const float* pos       = (const float*)d_in[9];
  const float* blk_ln_g  = (const float*)d_in[10];
  const float* blk_ln_b  = (const float*)d_in[11];
  const float* in_proj_w = (const float*)d_in[12];
  const float* conv_w    = (const float*)d_in[13];
  const float* conv_b    = (const float*)d_in[14];
  const float* x_proj_w  = (const float*)d_in[15];
  const float* dt_proj_w = (const float*)d_in[16];
  const float* dt_proj_b = (const float*)d_in[17];
  const float* A_log     = (const float*)d_in[18];
  const float* Dskip     = (const float*)d_in[19];
  const float* out_proj_w= (const float*)d_in[20];
  const float* fin_g     = (const float*)d_in[21];
  const float* fin_b     = (const float*)d_in[22];

  char* p = (char*)d_ws;
  float*  h     = (float*)p;  p += (size_t)NROWS*512*4;      // 8 MB
  float*  outP  = (float*)p;  p += (size_t)4*NROWS*512*4;    // 32 MB (out_proj parts)
  float*  projP = (float*)p;  p += (size_t)2*4*NROWS*64*4;   // 8 MB (x_proj parts)
  __bf16* hnb   = (__bf16*)p; p += (size_t)NROWS*512*2;      // 4 MB
  __bf16* ucb2  = (__bf16*)p; p += (size_t)2*NROWS*1024*2;   // 16 MB
  __bf16* szb2  = (__bf16*)p; p += (size_t)2*NROWS*1024*2;   // 16 MB
  __bf16* dtb2  = (__bf16*)p; p += (size_t)2*NROWS*1024*2;   // 16 MB
  __bf16* gbK   = (__bf16*)p; p += (size_t)NROWS*2048*2;     // 16 MB
  __bf16* projb2=(__bf16*)p;  p += (size_t)2*NROWS*64*2;     // 1 MB
  __bf16* wtin  = (__bf16*)p; p += (size_t)4*2048*512*2;     // 8 MB
  __bf16* wtoutK=(__bf16*)p;  p += (size_t)2*512*2048*2;     // 4 MB
  __bf16* wtx   = (__bf16*)p; p += (size_t)4*64*1024*2;      // 0.5 MB
  __bf16* wdtT  = (__bf16*)p; p += (size_t)4*1024*32*2;      // 0.25 MB
  __bf16* Abuf  = (__bf16*)p; p += (size_t)NROWS*KPAD*2;     // 0.75 MB
  __bf16* pwb   = (__bf16*)p; p += (size_t)512*KPAD*2;       // 96 KB

  // ---- weight prep ----
  transpose_bf16_kernel<<<dim3(64, 16, 4), dim3(32,8), 0, stream>>>(
      in_proj_w, wtin, 512, 2048);
  transpose_outw_kernel<<<dim3(16, 32, 4), dim3(32,8), 0, stream>>>(
      out_proj_w, wtoutK);
  transpose_bf16_kernel<<<dim3(2, 32, 4), dim3(32,8), 0, stream>>>(
      x_proj_w, wtx, 1024, 64);
  transpose_bf16_kernel<<<dim3(32, 1, 4), dim3(32,8), 0, stream>>>(
      dt_proj_w, wdtT, 32, 1024);
  cast_pad_pw_kernel<<<(512*KPAD + 255)/256, 256, 0, stream>>>(patch_w, pwb);

  // ---- patch embed ---- (f32 scratch = outP region)
  bn_patchify_kernel<<<(NROWS*KPAD)/256, 256, 0, stream>>>(
      x, bn_gamma, bn_beta, bn_mean, bn_var, Abuf);
  mfma_gemm<128,128,32,1,0><<<dim3(4, 32, 1), 256, 0, stream>>>(
      Abuf, pwb, outP, nullptr, nullptr, 512, KPAD, KPAD, KPAD,
      0,0,0, 0,0,0, 0);
  ln_pos_ln_kernel<<<NROWS, 256, 0, stream>>>(
      outP, patch_b, ln_pg, ln_pb, pos, blk_ln_g, blk_ln_b, h, hnb);

  for(int i=0;i<2;i++){
    // in_proj both dirs + conv + silu -> ucb2/szb2 (bf16, token order)
    mfma_inproj_conv<<<dim3(64, 32), 256, 0, stream>>>(
        hnb, wtin + (size_t)i*4096*512, conv_w + (size_t)i*2*4096,
        conv_b + (size_t)i*2*1024, ucb2, szb2);
    // x_proj split-K=4, both dirs in one launch (z = dir*4 + kslice)
    mfma_gemm<64,64,64,4,0><<<dim3(1, 64, 8), 256, 0, stream>>>(
        ucb2, wtx + (size_t)i*2*64*1024, projP, nullptr, nullptr,
        64, 256, 1024, 1024,
        256, 256, (size_t)NROWS*64,
        (size_t)NROWS*1024, (size_t)64*1024, (size_t)4*NROWS*64, 0);
    reduce_proj_kernel<<<(2*NROWS*64)/256, 256, 0, stream>>>(projP, projb2);
    // dt = softplus(dtr @ Wdt + bias) -> bf16 (z = dir)
    mfma_gemm<64,64,32,1,2><<<dim3(16, 64, 2), 256, 0, stream>>>(
        projb2, wdtT + (size_t)i*2*1024*32, nullptr, dtb2, dt_proj_b + (size_t)i*2*1024,
        1024, 32, 64, 32,
        0, 0, 0,
        (size_t)NROWS*64, (size_t)1024*32, (size_t)NROWS*1024, 1024);
    // scan both dirs -> gbK [row][2048]
    scan_kernel<<<dim3(BB, 8), 256, 0, stream>>>(
        dtb2, ucb2, projb2, szb2, A_log + (size_t)i*2*1024*16,
        Dskip + (size_t)i*2*1024, gbK);
    // out_proj split-K=4 -> outP parts (f32, coalesced)
    mfma_gemm<64,64,64,4,0><<<dim3(8, 64, 4), 256, 0, stream>>>(
        gbK, wtoutK + (size_t)i*512*2048, outP, nullptr, nullptr,
        512, 512, 2048, 2048,
        512, 512, (size_t)NROWS*512,
        0, 0, 0, 0);
    // h += sum(parts); next LN (layer-1 gamma/beta or final)
    if(i==0)
      reduce_ln_kernel<0><<<NROWS, 256, 0, stream>>>(
          outP, h, blk_ln_g + 512, blk_ln_b + 512, nullptr, hnb);
    else
      reduce_ln_kernel<1><<<NROWS, 256, 0, stream>>>(
          outP, h, fin_g, fin_b, (float*)d_out, nullptr);
  }
}

// Round 13
// 487.986 us; speedup vs baseline: 1.3452x; 1.0111x over previous
//
#include <hip/hip_runtime.h>
#include <math.h>
#include <stdint.h>

#define BB 256
#define C_IN 7
#define TT 160
#define PATCH 10
#define D_MODEL 512
#define L_TOK 16
#define D_INNER 1024
#define D_STATE 16
#define DT_RANK 32
#define EPS 1e-5f
#define NROWS (BB*L_TOK)   // 4096
#define KPAD 96            // 70 padded to 3*32

typedef __bf16 bf16x8 __attribute__((ext_vector_type(8)));
typedef __bf16 bf16x4 __attribute__((ext_vector_type(4)));
typedef float  f32x4  __attribute__((ext_vector_type(4)));

__device__ __forceinline__ float siluf(float x){ return x / (1.f + __expf(-x)); }
__device__ __forceinline__ float softplusf(float x){ return (x > 20.f) ? x : log1pf(__expf(x)); }

__device__ __forceinline__ void gload_lds16(const void* gp, void* lp){
  __builtin_amdgcn_global_load_lds(
      (const __attribute__((address_space(1))) unsigned int*)(uintptr_t)gp,
      (__attribute__((address_space(3))) unsigned int*)(uintptr_t)lp, 16, 0, 0);
}

__device__ __forceinline__ float block_reduce_sum(float v, float* sred4){
  for(int off=32; off>0; off>>=1) v += __shfl_down(v, off, 64);
  int lane = threadIdx.x & 63, wid = threadIdx.x >> 6;
  if(lane==0) sred4[wid] = v;
  __syncthreads();
  if(threadIdx.x==0) sred4[0] = sred4[0]+sred4[1]+sred4[2]+sred4[3];
  __syncthreads();
  float r = sred4[0];
  __syncthreads();
  return r;
}

// ---------------------------------------------------------------------------
// prep_all: all weight transposes + patch_w cast + bn_patchify in ONE kernel.
// Linear block ranges:
//  [0,4096)     in_proj  [z=4][512][2048] -> wtin [z][2048][512]
//  [4096,6144)  out_proj [z=4][1024][512] -> wtoutK [layer][512][2048] K-concat
//  [6144,6400)  x_proj   [z=4][1024][64]  -> wtx [z][64][1024]
//  [6400,6528)  dt_proj  [z=4][32][1024]  -> wdtT [z][1024][32]
//  [6528,6720)  patch_w cast+pad -> pwb [512][96]
//  [6720,8256)  bn+patchify -> Abuf [4096][96]
// ---------------------------------------------------------------------------
__global__ __launch_bounds__(256) void prep_all(
    const float* __restrict__ in_proj_w, const float* __restrict__ out_proj_w,
    const float* __restrict__ x_proj_w,  const float* __restrict__ dt_proj_w,
    const float* __restrict__ patch_w,   const float* __restrict__ x,
    const float* __restrict__ bng, const float* __restrict__ bnb,
    const float* __restrict__ bnm, const float* __restrict__ bnv,
    __bf16* __restrict__ wtin, __bf16* __restrict__ wtoutK,
    __bf16* __restrict__ wtx,  __bf16* __restrict__ wdtT,
    __bf16* __restrict__ pwb,  __bf16* __restrict__ Abuf)
{
  __shared__ float tile[32][33];
  int B = blockIdx.x;
  int tid = threadIdx.x;
  int tx = tid & 31, ty = tid >> 5;

  if(B < 4096){                                  // in_proj: K=512, N=2048
    int z = B >> 10, rem = B & 1023;
    int nx = rem & 63, ky = rem >> 6;
    int n0 = nx*32, k0 = ky*32;
    const float* ip = in_proj_w + (size_t)z*512*2048;
    #pragma unroll
    for(int rr=0;rr<4;rr++)
      tile[ty+rr*8][tx] = ip[(size_t)(k0+ty+rr*8)*2048 + n0+tx];
    __syncthreads();
    __bf16* op = wtin + (size_t)z*2048*512;
    #pragma unroll
    for(int rr=0;rr<4;rr++)
      op[(size_t)(n0+ty+rr*8)*512 + k0+tx] = (__bf16)tile[tx][ty+rr*8];
  } else if(B < 6144){                           // out_proj: K=1024, N=512
    int B2 = B-4096; int z = B2 >> 9, rem = B2 & 511;
    int nx = rem & 15, ky = rem >> 4;
    int n0 = nx*32, k0 = ky*32;
    const float* ip = out_proj_w + (size_t)z*1024*512;
    #pragma unroll
    for(int rr=0;rr<4;rr++)
      tile[ty+rr*8][tx] = ip[(size_t)(k0+ty+rr*8)*512 + n0+tx];
    __syncthreads();
    int layer = z>>1, dir = z&1;
    __bf16* op = wtoutK + (size_t)layer*512*2048 + (size_t)dir*1024;
    #pragma unroll
    for(int rr=0;rr<4;rr++)
      op[(size_t)(n0+ty+rr*8)*2048 + k0+tx] = (__bf16)tile[tx][ty+rr*8];
  } else if(B < 6400){                           // x_proj: K=1024, N=64
    int B2 = B-6144; int z = B2 >> 6, rem = B2 & 63;
    int nx = rem & 1, ky = rem >> 1;
    int n0 = nx*32, k0 = ky*32;
    const float* ip = x_proj_w + (size_t)z*1024*64;
    #pragma unroll
    for(int rr=0;rr<4;rr++)
      tile[ty+rr*8][tx] = ip[(size_t)(k0+ty+rr*8)*64 + n0+tx];
    __syncthreads();
    __bf16* op = wtx + (size_t)z*64*1024;
    #pragma unroll
    for(int rr=0;rr<4;rr++)
      op[(size_t)(n0+ty+rr*8)*1024 + k0+tx] = (__bf16)tile[tx][ty+rr*8];
  } else if(B < 6528){                           // dt_proj: K=32, N=1024
    int B2 = B-6400; int z = B2 >> 5, nx = B2 & 31;
    int n0 = nx*32, k0 = 0;
    const float* ip = dt_proj_w + (size_t)z*32*1024;
    #pragma unroll
    for(int rr=0;rr<4;rr++)
      tile[ty+rr*8][tx] = ip[(size_t)(k0+ty+rr*8)*1024 + n0+tx];
    __syncthreads();
    __bf16* op = wdtT + (size_t)z*1024*32;
    #pragma unroll
    for(int rr=0;rr<4;rr++)
      op[(size_t)(n0+ty+rr*8)*32 + k0+tx] = (__bf16)tile[tx][ty+rr*8];
  } else if(B < 6720){                           // patch_w cast+pad
    int idx = (B-6528)*256 + tid;                // 512*96
    int n = idx / KPAD, k = idx % KPAD;
    pwb[idx] = (__bf16)(k < C_IN*PATCH ? patch_w[n*(C_IN*PATCH) + k] : 0.f);
  } else {                                       // bn + patchify
    int idx = (B-6720)*256 + tid;                // 4096*96
    int row = idx / KPAD, k = idx % KPAD;
    int b = row >> 4, l = row & 15;
    float v = 0.f;
    if(k < C_IN*PATCH){
      int c = k / PATCH, j = k % PATCH;
      float xv = x[(b*C_IN + c)*TT + l*PATCH + j];
      v = (xv - bnm[c]) * rsqrtf(bnv[c] + EPS) * bng[c] + bnb[c];
    }
    Abuf[idx] = (__bf16)v;
  }
}

// split-K reduce: part[dir][4][4096][64] f32 -> projb[dir][4096][64] bf16
__global__ __launch_bounds__(256) void reduce_proj_kernel(
    const float* __restrict__ part, __bf16* __restrict__ projb)
{
  int idx = blockIdx.x*256 + threadIdx.x;     // over 2*4096*64
  int dir = idx / (NROWS*64);
  int rem = idx - dir*(NROWS*64);
  const float* p0 = part + (size_t)dir*4*NROWS*64 + rem;
  float s = p0[0] + p0[(size_t)NROWS*64] + p0[(size_t)2*NROWS*64] + p0[(size_t)3*NROWS*64];
  projb[idx] = (__bf16)s;
}

// ---------------------------------------------------------------------------
// out_proj parts reduce + residual + LayerNorm.
// ---------------------------------------------------------------------------
template<int FINAL>
__global__ __launch_bounds__(256) void reduce_ln_kernel(
    const float* __restrict__ parts, float* __restrict__ h,
    const float* __restrict__ g, const float* __restrict__ bt,
    float* __restrict__ outf, __bf16* __restrict__ outb)
{
  __shared__ float sred[4];
  int row = blockIdx.x; int tid = threadIdx.x;
  size_t o0 = (size_t)row*512 + tid, o1 = o0 + 256;
  float v0 = h[o0], v1 = h[o1];
  #pragma unroll
  for(int ks=0;ks<4;ks++){
    v0 += parts[(size_t)ks*NROWS*512 + o0];
    v1 += parts[(size_t)ks*NROWS*512 + o1];
  }
  h[o0] = v0; h[o1] = v1;
  float s = block_reduce_sum(v0+v1, sred);
  float mean = s * (1.f/512.f);
  float d0 = v0-mean, d1 = v1-mean;
  float vs = block_reduce_sum(d0*d0+d1*d1, sred);
  float rstd = rsqrtf(vs*(1.f/512.f) + EPS);
  float r0 = d0*rstd*g[tid]     + bt[tid];
  float r1 = d1*rstd*g[tid+256] + bt[tid+256];
  if(FINAL){ outf[o0] = r0; outf[o1] = r1; }
  else     { outb[o0] = (__bf16)r0; outb[o1] = (__bf16)r1; }
}

// ---------------------------------------------------------------------------
// Generic MFMA bf16 GEMM (swapped-operand epilogue). EPI: 0 plain f32;
// 2 bf16 softplus+bias; 3 bf16-only. z decomposition: zi = z % ZDIV (inner,
// strides sA/sB/sC), zo = z / ZDIV (outer, strides sAo/sBo/sCo; bias zo*sBias).
// ---------------------------------------------------------------------------
template<int BM, int BN, int BK, int ZDIV, int EPI>
__global__ __launch_bounds__(256) void mfma_gemm(
    const __bf16* __restrict__ A, const __bf16* __restrict__ Bt,
    float* __restrict__ C, __bf16* __restrict__ Cb,
    const float* __restrict__ bias, int N, int K, int lda, int ldb,
    size_t sA, size_t sB, size_t sC,
    size_t sAo, size_t sBo, size_t sCo, size_t sBias)
{
  constexpr int NGA = BM/16, NGB = BN/16;
  constexpr int APW = NGA/4, BPW = NGB/4;
  constexpr int MI  = BM/32, FN  = BN/32;
  constexpr int NSL = BK/32;
  __shared__ __align__(16) __bf16 As[NSL*NGA*512];
  __shared__ __align__(16) __bf16 Bs[NSL*NGB*512];
  int z = blockIdx.z;
  int zi = z % ZDIV, zo = z / ZDIV;
  A  += (size_t)zi*sA + (size_t)zo*sAo;
  Bt += (size_t)zi*sB + (size_t)zo*sBo;
  if(EPI==0) C  += (size_t)zi*sC + (size_t)zo*sCo;
  else       Cb += (size_t)zi*sC + (size_t)zo*sCo;
  if(EPI==2) bias += (size_t)zo*sBias;
  int tid  = threadIdx.x;
  int lane = tid & 63, w = tid >> 6;
  int wrow = w >> 1, wcol = w & 1;
  int r = lane & 15, q = lane >> 4;
  int row0 = blockIdx.y*BM, col0 = blockIdx.x*BN;

  f32x4 acc[MI][FN];
  #pragma unroll
  for(int i=0;i<MI;i++)
    #pragma unroll
    for(int j=0;j<FN;j++) acc[i][j] = (f32x4)0.f;

  const __bf16* aSrc[APW];
  #pragma unroll
  for(int g=0;g<APW;g++)
    aSrc[g] = A + (size_t)(row0 + (w*APW+g)*16 + r)*lda + q*8;
  const __bf16* bSrc[BPW];
  #pragma unroll
  for(int g=0;g<BPW;g++)
    bSrc[g] = Bt + (size_t)(col0 + (w*BPW+g)*16 + r)*ldb + q*8;

  for(int k0=0;k0<K;k0+=BK){
    #pragma unroll
    for(int s=0;s<NSL;s++){
      #pragma unroll
      for(int g=0;g<APW;g++)
        gload_lds16(aSrc[g] + k0 + s*32, As + (s*NGA + w*APW+g)*512);
      #pragma unroll
      for(int g=0;g<BPW;g++)
        gload_lds16(bSrc[g] + k0 + s*32, Bs + (s*NGB + w*BPW+g)*512);
    }
    __syncthreads();
    #pragma unroll
    for(int s=0;s<NSL;s++){
      bf16x8 aF[MI], bF[FN];
      #pragma unroll
      for(int i=0;i<MI;i++)
        aF[i] = *(const bf16x8*)(As + (s*NGA + wrow*MI+i)*512 + lane*8);
      #pragma unroll
      for(int j=0;j<FN;j++)
        bF[j] = *(const bf16x8*)(Bs + (s*NGB + wcol*FN+j)*512 + lane*8);
      #pragma unroll
      for(int i=0;i<MI;i++)
        #pragma unroll
        for(int j=0;j<FN;j++)
          acc[i][j] = __builtin_amdgcn_mfma_f32_16x16x32_bf16(bF[j], aF[i], acc[i][j], 0, 0, 0);
    }
    __syncthreads();
  }

  #pragma unroll
  for(int i=0;i<MI;i++){
    int m = row0 + wrow*(BM/2) + i*16 + r;
    #pragma unroll
    for(int j=0;j<FN;j++){
      int n = col0 + wcol*(BN/2) + j*16 + q*4;
      if(EPI==2){
        const float* bp = bias + n;
        bf16x4 hv;
        #pragma unroll
        for(int p=0;p<4;p++) hv[p] = (__bf16)softplusf(acc[i][j][p] + bp[p]);
        *(bf16x4*)(Cb + (size_t)m*N + n) = hv;
      } else if(EPI==3){
        bf16x4 hv;
        #pragma unroll
        for(int p=0;p<4;p++) hv[p] = (__bf16)acc[i][j][p];
        *(bf16x4*)(Cb + (size_t)m*N + n) = hv;
      } else {
        *(f32x4*)(C + (size_t)m*N + n) = acc[i][j];
      }
    }
  }
}

// ---------------------------------------------------------------------------
// in_proj GEMM (R8 form — empirical floor). dirs N-concat, BM=128, BN=64,
// BK=64, grid 64x32, XCD swizzle, fused conv(4)+SiLU via lane shuffles.
// ---------------------------------------------------------------------------
__global__ __launch_bounds__(256, 3) void mfma_inproj_conv(
    const __bf16* __restrict__ A, const __bf16* __restrict__ Bt,
    const float* __restrict__ cw, const float* __restrict__ cb,
    __bf16* __restrict__ ucb, __bf16* __restrict__ szb)
{
  constexpr int LDA = 512, LDB = 512, K = 512;
  __shared__ __align__(16) __bf16 As[2*8*512];
  __shared__ __align__(16) __bf16 Bs[2*4*512];
  __shared__ float4 s_w4[64];
  __shared__ float  s_b[64];
  int tid  = threadIdx.x;
  int lane = tid & 63, w = tid >> 6;
  int wrow = w >> 1, wcol = w & 1;
  int r = lane & 15, q = lane >> 4;

  int lin  = blockIdx.x + gridDim.x*blockIdx.y;
  int xcd  = lin & 7;
  int idx  = lin >> 3;
  int colb = xcd*8 + (idx & 7);
  int rowb = idx >> 3;
  int row0 = rowb*128, col0 = colb*64;

  int dirq = col0 >> 11;
  int feat0 = col0 & 2047;
  bool is_u = feat0 < 1024;
  int dblk = col0 & 1023;
  if(is_u && tid < 64){
    s_w4[tid] = ((const float4*)(cw + dirq*4096))[dblk + tid];
    s_b[tid]  = (cb + dirq*1024)[dblk + tid];
  }

  f32x4 acc[4][2];
  #pragma unroll
  for(int i=0;i<4;i++)
    #pragma unroll
    for(int j=0;j<2;j++) acc[i][j] = (f32x4)0.f;

  const __bf16* aSrc[2];
  #pragma unroll
  for(int g=0;g<2;g++)
    aSrc[g] = A + (size_t)(row0 + (w*2+g)*16 + r)*LDA + q*8;
  const __bf16* bSrc0 = Bt + (size_t)(col0 + w*16 + r)*LDB + q*8;

  for(int k0=0;k0<K;k0+=64){
    #pragma unroll
    for(int s=0;s<2;s++){
      #pragma unroll
      for(int g=0;g<2;g++)
        gload_lds16(aSrc[g] + k0 + s*32, As + (s*8 + w*2+g)*512);
      gload_lds16(bSrc0 + k0 + s*32, Bs + (s*4 + w)*512);
    }
    __syncthreads();
    #pragma unroll
    for(int s=0;s<2;s++){
      bf16x8 aF[4], bF[2];
      #pragma unroll
      for(int i=0;i<4;i++)
        aF[i] = *(const bf16x8*)(As + (s*8 + wrow*4+i)*512 + lane*8);
      #pragma unroll
      for(int j=0;j<2;j++)
        bF[j] = *(const bf16x8*)(Bs + (s*4 + wcol*2+j)*512 + lane*8);
      #pragma unroll
      for(int i=0;i<4;i++)
        #pragma unroll
        for(int j=0;j<2;j++)
          acc[i][j] = __builtin_amdgcn_mfma_f32_16x16x32_bf16(bF[j], aF[i], acc[i][j], 0, 0, 0);
    }
    __syncthreads();
  }

  __bf16* ucbD = ucb + (size_t)dirq*NROWS*1024;
  __bf16* szD  = szb + (size_t)dirq*NROWS*1024;

  #pragma unroll
  for(int i=0;i<4;i++){
    int tok = row0 + wrow*64 + i*16 + r;
    #pragma unroll
    for(int j=0;j<2;j++){
      int nloc = wcol*32 + j*16 + q*4;
      if(is_u){
        int f = nloc;
        int d = dblk + f;
        float vout[4];
        if(dirq==0){
          #pragma unroll
          for(int p=0;p<4;p++){
            float cur = acc[i][j][p];
            float m1 = __shfl_up(cur, 1, 64);
            float m2 = __shfl_up(cur, 2, 64);
            float m3 = __shfl_up(cur, 3, 64);
            float4 w4 = s_w4[f+p];
            float v = s_b[f+p] + w4.w*cur;
            v += (r>=1)? w4.z*m1 : 0.f;
            v += (r>=2)? w4.y*m2 : 0.f;
            v += (r>=3)? w4.x*m3 : 0.f;
            vout[p] = v;
          }
        } else {
          #pragma unroll
          for(int p=0;p<4;p++){
            float cur = acc[i][j][p];
            float p1 = __shfl_down(cur, 1, 64);
            float p2 = __shfl_down(cur, 2, 64);
            float p3 = __shfl_down(cur, 3, 64);
            float4 w4 = s_w4[f+p];
            float v = s_b[f+p] + w4.w*cur;
            v += (r<=14)? w4.z*p1 : 0.f;
            v += (r<=13)? w4.y*p2 : 0.f;
            v += (r<=12)? w4.x*p3 : 0.f;
            vout[p] = v;
          }
        }
        bf16x4 hv;
        #pragma unroll
        for(int p=0;p<4;p++) hv[p] = (__bf16)siluf(vout[p]);
        *(bf16x4*)(ucbD + (size_t)tok*1024 + d) = hv;
      } else {
        int dz = feat0 - 1024 + nloc;
        bf16x4 hv;
        #pragma unroll
        for(int p=0;p<4;p++) hv[p] = (__bf16)siluf(acc[i][j][p]);
        *(bf16x4*)(szD + (size_t)tok*1024 + dz) = hv;
      }
    }
  }
}

// ---------------------------------------------------------------------------
// bias + LN + pos -> h (f32), then LN with layer-0 gamma/beta -> hnb bf16
// ---------------------------------------------------------------------------
__global__ __launch_bounds__(256) void ln_pos_ln_kernel(
    const float* __restrict__ in, const float* __restrict__ pb,
    const float* __restrict__ g1, const float* __restrict__ b1,
    const float* __restrict__ pos, const float* __restrict__ g2,
    const float* __restrict__ b2, float* __restrict__ h,
    __bf16* __restrict__ hnb)
{
  __shared__ float sred[4];
  int row = blockIdx.x; int l = row & 15; int tid = threadIdx.x;
  const float* ip = in + (size_t)row*512;
  float v0 = ip[tid] + pb[tid], v1 = ip[tid+256] + pb[tid+256];
  float s = block_reduce_sum(v0+v1, sred);
  float mean = s * (1.f/512.f);
  float d0 = v0-mean, d1 = v1-mean;
  float vs = block_reduce_sum(d0*d0+d1*d1, sred);
  float rstd = rsqrtf(vs*(1.f/512.f) + EPS);
  float h0 = d0*rstd*g1[tid]     + b1[tid]     + pos[l*512+tid];
  float h1 = d1*rstd*g1[tid+256] + b1[tid+256] + pos[l*512+tid+256];
  h[(size_t)row*512+tid]     = h0;
  h[(size_t)row*512+tid+256] = h1;
  float s2 = block_reduce_sum(h0+h1, sred);
  float mean2 = s2 * (1.f/512.f);
  float e0 = h0-mean2, e1 = h1-mean2;
  float vs2 = block_reduce_sum(e0*e0+e1*e1, sred);
  float rstd2 = rsqrtf(vs2*(1.f/512.f) + EPS);
  hnb[(size_t)row*512+tid]     = (__bf16)(e0*rstd2*g2[tid]     + b2[tid]);
  hnb[(size_t)row*512+tid+256] = (__bf16)(e1*rstd2*g2[tid+256] + b2[tid+256]);
}

// ---------------------------------------------------------------------------
// selective scan, both dirs (gridDim.y=8: dir = y>>2). dt/uc/sz/proj bf16,
// token order. gb out: [row][2048] bf16 K-concat for out_proj.
// ---------------------------------------------------------------------------
__global__ __launch_bounds__(256) void scan_kernel(
    const __bf16* __restrict__ dtb, const __bf16* __restrict__ ucb,
    const __bf16* __restrict__ projb, const __bf16* __restrict__ szb,
    const float* __restrict__ A_log, const float* __restrict__ Dskip,
    __bf16* __restrict__ gb)
{
  int b = blockIdx.x;
  int dirq = blockIdx.y >> 2;
  int d = (blockIdx.y & 3)*256 + threadIdx.x;
  const __bf16* dtp = dtb + (size_t)dirq*NROWS*1024;
  const __bf16* ucp = ucb + (size_t)dirq*NROWS*1024;
  const __bf16* prp = projb + (size_t)dirq*NROWS*64;
  const __bf16* szp = szb  + (size_t)dirq*NROWS*1024;
  const float*  Alp = A_log + (size_t)dirq*1024*16;
  float Dv = Dskip[dirq*1024 + d];
  __shared__ float sB[16][16], sC[16][16];
  {
    int s = threadIdx.x >> 4, n = threadIdx.x & 15;
    int tok = dirq ? 15-s : s;
    sB[s][n] = (float)prp[(size_t)(b*16+tok)*64 + 32 + n];
    sC[s][n] = (float)prp[(size_t)(b*16+tok)*64 + 48 + n];
  }
  __syncthreads();
  float a[16], hst[16];
  #pragma unroll
  for(int n=0;n<16;n++){ a[n] = -__expf(Alp[d*16+n]); hst[n]=0.f; }
  for(int s=0;s<16;s++){
    int tok = dirq ? 15-s : s;
    size_t o = (size_t)(b*16+tok)*1024 + d;
    float dtv = (float)dtp[o];
    float ucv = (float)ucp[o];
    float dtu = dtv*ucv;
    float y = 0.f;
    #pragma unroll
    for(int n=0;n<16;n++){
      hst[n] = __expf(dtv*a[n])*hst[n] + dtu*sB[s][n];
      y += hst[n]*sC[s][n];
    }
    float zs = (float)szp[o];
    gb[(size_t)(b*16+tok)*2048 + dirq*1024 + d] = (__bf16)((y + ucv*Dv) * zs);
  }
}

// ---------------------------------------------------------------------------
extern "C" void kernel_launch(void* const* d_in, const int* in_sizes, int n_in,
                              void* d_out, int out_size, void* d_ws, size_t ws_size,
                              hipStream_t stream) {
  (void)in_sizes; (void)n_in; (void)out_size; (void)ws_size;
  const float* x         = (const float*)d_in[0];
  const float* bn_gamma  = (const float*)d_in[1];
  const float* bn_beta   = (const float*)d_in[2];
  const float* bn_mean   = (const float*)d_in[3];
  const float* bn_var    = (const float*)d_in[4];
  const float* patch_w   = (const float*)d_in[5];
  const float* patch_b   = (const float*)d_in[6];
  const float* ln_pg     = (const float*)d_in[7];
  const float* ln_pb     = (const float*)d_in[8];
  const float* pos       = (const float*)d_in[9];
  const float* blk_ln_g  = (const float*)d_in[10];
  const float* blk_ln_b  = (const float*)d_in[11];
  const float* in_proj_w = (const float*)d_in[12];
  const float* conv_w    = (const float*)d_in[13];
  const float* conv_b    = (const float*)d_in[14];
  const float* x_proj_w  = (const float*)d_in[15];
  const float* dt_proj_w = (const float*)d_in[16];
  const float* dt_proj_b = (const float*)d_in[17];
  const float* A_log     = (const float*)d_in[18];
  const float* Dskip     = (const float*)d_in[19];
  const float* out_proj_w= (const float*)d_in[20];
  const float* fin_g     = (const float*)d_in[21];
  const float* fin_b     = (const float*)d_in[22];

  char* p = (char*)d_ws;
  float*  h     = (float*)p;  p += (size_t)NROWS*512*4;      // 8 MB
  float*  outP  = (float*)p;  p += (size_t)4*NROWS*512*4;    // 32 MB (out_proj parts / patch scratch)
  float*  projP = (float*)p;  p += (size_t)2*4*NROWS*64*4;   // 8 MB (x_proj parts)
  __bf16* hnb   = (__bf16*)p; p += (size_t)NROWS*512*2;      // 4 MB
  __bf16* ucb2  = (__bf16*)p; p += (size_t)2*NROWS*1024*2;   // 16 MB
  __bf16* szb2  = (__bf16*)p; p += (size_t)2*NROWS*1024*2;   // 16 MB
  __bf16* dtb2  = (__bf16*)p; p += (size_t)2*NROWS*1024*2;   // 16 MB
  __bf16* gbK   = (__bf16*)p; p += (size_t)NROWS*2048*2;     // 16 MB
  __bf16* projb2=(__bf16*)p;  p += (size_t)2*NROWS*64*2;     // 1 MB
  __bf16* wtin  = (__bf16*)p; p += (size_t)4*2048*512*2;     // 8 MB
  __bf16* wtoutK=(__bf16*)p;  p += (size_t)2*512*2048*2;     // 4 MB
  __bf16* wtx   = (__bf16*)p; p += (size_t)4*64*1024*2;      // 0.5 MB
  __bf16* wdtT  = (__bf16*)p; p += (size_t)4*1024*32*2;      // 0.25 MB
  __bf16* Abuf  = (__bf16*)p; p += (size_t)NROWS*KPAD*2;     // 0.75 MB
  __bf16* pwb   = (__bf16*)p; p += (size_t)512*KPAD*2;       // 96 KB

  // single prep kernel: all transposes + pw cast + bn/patchify
  prep_all<<<8256, 256, 0, stream>>>(
      in_proj_w, out_proj_w, x_proj_w, dt_proj_w, patch_w,
      x, bn_gamma, bn_beta, bn_mean, bn_var,
      wtin, wtoutK, wtx, wdtT, pwb, Abuf);

  // patch embed GEMM -> outP scratch -> fused bias+LN+pos+LN
  mfma_gemm<128,128,32,1,0><<<dim3(4, 32, 1), 256, 0, stream>>>(
      Abuf, pwb, outP, nullptr, nullptr, 512, KPAD, KPAD, KPAD,
      0,0,0, 0,0,0, 0);
  ln_pos_ln_kernel<<<NROWS, 256, 0, stream>>>(
      outP, patch_b, ln_pg, ln_pb, pos, blk_ln_g, blk_ln_b, h, hnb);

  for(int i=0;i<2;i++){
    // in_proj both dirs + conv + silu -> ucb2/szb2 (bf16, token order)
    mfma_inproj_conv<<<dim3(64, 32), 256, 0, stream>>>(
        hnb, wtin + (size_t)i*4096*512, conv_w + (size_t)i*2*4096,
        conv_b + (size_t)i*2*1024, ucb2, szb2);
    // x_proj split-K=4, both dirs in one launch (z = dir*4 + kslice)
    mfma_gemm<64,64,64,4,0><<<dim3(1, 64, 8), 256, 0, stream>>>(
        ucb2, wtx + (size_t)i*2*64*1024, projP, nullptr, nullptr,
        64, 256, 1024, 1024,
        256, 256, (size_t)NROWS*64,
        (size_t)NROWS*1024, (size_t)64*1024, (size_t)4*NROWS*64, 0);
    reduce_proj_kernel<<<(2*NROWS*64)/256, 256, 0, stream>>>(projP, projb2);
    // dt = softplus(dtr @ Wdt + bias) -> bf16 (z = dir)
    mfma_gemm<64,64,32,1,2><<<dim3(16, 64, 2), 256, 0, stream>>>(
        projb2, wdtT + (size_t)i*2*1024*32, nullptr, dtb2, dt_proj_b + (size_t)i*2*1024,
        1024, 32, 64, 32,
        0, 0, 0,
        (size_t)NROWS*64, (size_t)1024*32, (size_t)NROWS*1024, 1024);
    // scan both dirs -> gbK [row][2048]
    scan_kernel<<<dim3(BB, 8), 256, 0, stream>>>(
        dtb2, ucb2, projb2, szb2, A_log + (size_t)i*2*1024*16,
        Dskip + (size_t)i*2*1024, gbK);
    // out_proj split-K=4 -> outP parts (f32, coalesced)
    mfma_gemm<64,64,64,4,0><<<dim3(8, 64, 4), 256, 0, stream>>>(
        gbK, wtoutK + (size_t)i*512*2048, outP, nullptr, nullptr,
        512, 512, 2048, 2048,
        512, 512, (size_t)NROWS*512,
        0, 0, 0, 0);
    // h += sum(parts); next LN (layer-1 or final)
    if(i==0)
      reduce_ln_kernel<0><<<NROWS, 256, 0, stream>>>(
          outP, h, blk_ln_g + 512, blk_ln_b + 512, nullptr, hnb);
    else
      reduce_ln_kernel<1><<<NROWS, 256, 0, stream>>>(
          outP, h, fin_g, fin_b, (float*)d_out, nullptr);
  }
}